// Round 1
// baseline (363.810 us; speedup 1.0000x reference)
//
#include <hip/hip_runtime.h>

typedef __attribute__((ext_vector_type(8))) short bf16x8;
typedef __attribute__((ext_vector_type(4))) float f32x4;
typedef __attribute__((ext_vector_type(4))) unsigned short us4;

#define SCALE 0.125f

__device__ __forceinline__ unsigned short f2bf(float f) {
    unsigned int u = __float_as_uint(f);
    u = (u + 0x7FFF + ((u >> 16) & 1)) >> 16;   // RNE
    return (unsigned short)u;
}

// ---------------- prep kernels ----------------

__global__ __launch_bounds__(256) void convx(const float* __restrict__ X,
                                             unsigned short* __restrict__ O) {
    int i = blockIdx.x * 256 + threadIdx.x;
    float4 v = ((const float4*)X)[i];
    us4 o;
    o.x = f2bf(v.x); o.y = f2bf(v.y); o.z = f2bf(v.z); o.w = f2bf(v.w);
    ((us4*)O)[i] = o;
}

// W [Kd][Cd] fp32  ->  WT [Cd][Kd] bf16
__global__ __launch_bounds__(256) void transposew(const float* __restrict__ W,
                                                  unsigned short* __restrict__ WT,
                                                  int Kd, int Cd) {
    __shared__ float t[32][33];
    int c0 = blockIdx.x * 32, k0 = blockIdx.y * 32;
    int tx = threadIdx.x & 31, ty = threadIdx.x >> 5;  // ty 0..7
#pragma unroll
    for (int i = 0; i < 32; i += 8)
        t[ty + i][tx] = W[(size_t)(k0 + ty + i) * Cd + c0 + tx];
    __syncthreads();
#pragma unroll
    for (int i = 0; i < 32; i += 8)
        WT[(size_t)(c0 + ty + i) * Kd + k0 + tx] = f2bf(t[tx][ty + i]);
}

__global__ __launch_bounds__(256) void packmask(const int* __restrict__ Mi,
                                                unsigned int* __restrict__ Mo) {
    int i = blockIdx.x * 256 + threadIdx.x;
    int4 v = ((const int4*)Mi)[i];
    Mo[i] = (unsigned)(v.x & 1) | ((unsigned)(v.y & 1) << 8) |
            ((unsigned)(v.z & 1) << 16) | ((unsigned)(v.w & 1) << 24);
}

// ---------------- GEMM: C = A[M][K] * BT[N][K]^T ----------------
// MODE 0: scatter epilogue -> Q [bh][l][d], K [bh][l][d], VT [bh][d][l] (bf16)
// MODE 1: + bias -> fp32 out
template <int MODE>
__global__ __launch_bounds__(256) void gemm_bf16(
    const unsigned short* __restrict__ A, const unsigned short* __restrict__ BT,
    int M, int N, int K,
    unsigned short* __restrict__ Qo, unsigned short* __restrict__ Ko,
    unsigned short* __restrict__ Vo,
    const float* __restrict__ bias, float* __restrict__ Co) {
    __shared__ unsigned short Asub[128 * 64];
    __shared__ unsigned short Bsub[128 * 64];
    const int bm = blockIdx.y, bn = blockIdx.x;
    const int tid = threadIdx.x, w = tid >> 6, lane = tid & 63;
    const int wr = w >> 1, wc = w & 1, l16 = lane & 15, lg = lane >> 4;

    f32x4 acc[4][4];
#pragma unroll
    for (int i = 0; i < 4; i++)
#pragma unroll
        for (int j = 0; j < 4; j++) acc[i][j] = (f32x4){0.f, 0.f, 0.f, 0.f};

    const int r_st = tid >> 3;          // +i*32
    const int kc_st = (tid & 7) * 8;

    const int nkt = K / 64;
    for (int kt = 0; kt < nkt; kt++) {
        const int k0 = kt * 64;
#pragma unroll
        for (int i = 0; i < 4; i++) {
            int r = r_st + i * 32;
            uint4 va = *(const uint4*)(A + (size_t)(bm * 128 + r) * K + k0 + kc_st);
            uint4 vb = *(const uint4*)(BT + (size_t)(bn * 128 + r) * K + k0 + kc_st);
            int byt = (r * 128 + kc_st * 2) ^ ((r & 7) << 4);
            *(uint4*)((char*)Asub + byt) = va;
            *(uint4*)((char*)Bsub + byt) = vb;
        }
        __syncthreads();
#pragma unroll
        for (int ks = 0; ks < 2; ks++) {
            bf16x8 af[4], bfr[4];
            int kk = ks * 32 + lg * 8;
#pragma unroll
            for (int i = 0; i < 4; i++) {
                int r = wr * 64 + i * 16 + l16;
                af[i] = *(bf16x8*)((char*)Asub + ((r * 128 + kk * 2) ^ ((r & 7) << 4)));
                int c = wc * 64 + i * 16 + l16;
                bfr[i] = *(bf16x8*)((char*)Bsub + ((c * 128 + kk * 2) ^ ((c & 7) << 4)));
            }
#pragma unroll
            for (int i = 0; i < 4; i++)
#pragma unroll
                for (int j = 0; j < 4; j++)
                    acc[i][j] = __builtin_amdgcn_mfma_f32_16x16x32_bf16(
                        af[i], bfr[j], acc[i][j], 0, 0, 0);
        }
        __syncthreads();
    }

    if (MODE == 0) {
#pragma unroll
        for (int i = 0; i < 4; i++) {
            int grow = bm * 128 + wr * 64 + i * 16 + lg * 4;  // rows grow..grow+3
            int bb = grow >> 11, ll = grow & 2047;
#pragma unroll
            for (int j = 0; j < 4; j++) {
                int gcol = bn * 128 + wc * 64 + j * 16 + l16;
                int s = gcol >> 10, hh = (gcol >> 6) & 15, dd = gcol & 63;
                int bhh = bb * 16 + hh;
                if (s == 2) {
                    us4 pk;
                    pk.x = f2bf(acc[i][j][0]); pk.y = f2bf(acc[i][j][1]);
                    pk.z = f2bf(acc[i][j][2]); pk.w = f2bf(acc[i][j][3]);
                    *(us4*)(Vo + (size_t)(bhh * 64 + dd) * 2048 + ll) = pk;
                } else {
                    unsigned short* dst =
                        (s == 0 ? Qo : Ko) + (size_t)(bhh * 2048 + ll) * 64 + dd;
#pragma unroll
                    for (int r = 0; r < 4; r++) dst[(size_t)r * 64] = f2bf(acc[i][j][r]);
                }
            }
        }
    } else {
#pragma unroll
        for (int i = 0; i < 4; i++) {
            int grow = bm * 128 + wr * 64 + i * 16 + lg * 4;
#pragma unroll
            for (int j = 0; j < 4; j++) {
                int gcol = bn * 128 + wc * 64 + j * 16 + l16;
                float bv = bias[gcol];
#pragma unroll
                for (int r = 0; r < 4; r++)
                    Co[(size_t)(grow + r) * N + gcol] = acc[i][j][r] + bv;
            }
        }
    }
}

// ---------------- flash attention ----------------
// grid: (qt=32, bh=32), block 256 = 4 independent waves, 16 q-rows each.
__global__ __launch_bounds__(256) void flash_attn(
    const unsigned short* __restrict__ Q, const unsigned short* __restrict__ Kt,
    const unsigned short* __restrict__ VT, const unsigned char* __restrict__ M8,
    unsigned short* __restrict__ Z) {
    __shared__ unsigned short Plds[4 * 16 * 64];
    const int qt = blockIdx.x, bh = blockIdx.y;
    const int b = bh >> 4, h = bh & 15;
    const int tid = threadIdx.x, w = tid >> 6, lane = tid & 63;
    const int l16 = lane & 15, lg = lane >> 4;
    const int qb = qt * 64 + w * 16;

    const unsigned short* Qp = Q + (size_t)(bh * 2048 + qb + l16) * 64 + lg * 8;
    bf16x8 qf0 = *(const bf16x8*)Qp;
    bf16x8 qf1 = *(const bf16x8*)(Qp + 32);

    float m_r[4], l_r[4];
    f32x4 oacc[4];
#pragma unroll
    for (int r = 0; r < 4; r++) { m_r[r] = -__builtin_inff(); l_r[r] = 0.f; }
#pragma unroll
    for (int jd = 0; jd < 4; jd++) oacc[jd] = (f32x4){0.f, 0.f, 0.f, 0.f};

    char* pbase = (char*)Plds + w * 2048;
    const unsigned char* mrow = M8 + (size_t)(b * 2048 + qb + lg * 4) * 2048;

    for (int kt = 0; kt < 32; kt++) {
        const int lk0 = kt * 64;
        f32x4 sacc[4];
#pragma unroll
        for (int j = 0; j < 4; j++) sacc[j] = (f32x4){0.f, 0.f, 0.f, 0.f};
#pragma unroll
        for (int j = 0; j < 4; j++) {
            const unsigned short* Kp =
                Kt + (size_t)(bh * 2048 + lk0 + j * 16 + l16) * 64 + lg * 8;
            bf16x8 kf0 = *(const bf16x8*)Kp;
            bf16x8 kf1 = *(const bf16x8*)(Kp + 32);
            sacc[j] = __builtin_amdgcn_mfma_f32_16x16x32_bf16(qf0, kf0, sacc[j], 0, 0, 0);
            sacc[j] = __builtin_amdgcn_mfma_f32_16x16x32_bf16(qf1, kf1, sacc[j], 0, 0, 0);
        }
        // mask bytes for my 4 rows x 4 col-blocks
        float mv[4][4];
#pragma unroll
        for (int r = 0; r < 4; r++)
#pragma unroll
            for (int j = 0; j < 4; j++)
                mv[r][j] = (float)mrow[(size_t)r * 2048 + lk0 + j * 16 + l16];

        float p[4][4];
#pragma unroll
        for (int r = 0; r < 4; r++) {
            float s0 = sacc[0][r] * SCALE, s1 = sacc[1][r] * SCALE;
            float s2 = sacc[2][r] * SCALE, s3 = sacc[3][r] * SCALE;
            float mx = fmaxf(fmaxf(s0, s1), fmaxf(s2, s3));
#pragma unroll
            for (int off = 1; off < 16; off <<= 1) mx = fmaxf(mx, __shfl_xor(mx, off));
            float mn = fmaxf(m_r[r], mx);
            float alpha = __expf(m_r[r] - mn);
            float p0 = __expf(s0 - mn) * mv[r][0];
            float p1 = __expf(s1 - mn) * mv[r][1];
            float p2 = __expf(s2 - mn) * mv[r][2];
            float p3 = __expf(s3 - mn) * mv[r][3];
            float rs = p0 + p1 + p2 + p3;
#pragma unroll
            for (int off = 1; off < 16; off <<= 1) rs += __shfl_xor(rs, off);
            l_r[r] = l_r[r] * alpha + rs;
            m_r[r] = mn;
#pragma unroll
            for (int jd = 0; jd < 4; jd++) oacc[jd][r] *= alpha;
            p[r][0] = p0; p[r][1] = p1; p[r][2] = p2; p[r][3] = p3;
        }
        // P -> LDS (swizzled)
#pragma unroll
        for (int r = 0; r < 4; r++) {
            int rs_ = lg * 4 + r;
            int sw = (rs_ & 7) << 4;
#pragma unroll
            for (int j = 0; j < 4; j++) {
                int byt = (rs_ * 128 + (j * 16 + l16) * 2) ^ sw;
                *(unsigned short*)(pbase + byt) = f2bf(p[r][j]);
            }
        }
        __syncthreads();
        // PV
#pragma unroll
        for (int ks = 0; ks < 2; ks++) {
            int byt = (l16 * 128 + (ks * 32 + lg * 8) * 2) ^ ((l16 & 7) << 4);
            bf16x8 pf = *(bf16x8*)(pbase + byt);
#pragma unroll
            for (int jd = 0; jd < 4; jd++) {
                const unsigned short* Vp = VT + (size_t)(bh * 64 + jd * 16 + l16) * 2048 +
                                           lk0 + ks * 32 + lg * 8;
                bf16x8 vf = *(const bf16x8*)Vp;
                oacc[jd] = __builtin_amdgcn_mfma_f32_16x16x32_bf16(pf, vf, oacc[jd], 0, 0, 0);
            }
        }
        __syncthreads();
    }

#pragma unroll
    for (int r = 0; r < 4; r++) {
        float inv = 1.0f / (l_r[r] + 1e-20f);
        int qrow = qb + lg * 4 + r;
        unsigned short* zp = Z + (size_t)(b * 2048 + qrow) * 1024 + h * 64 + l16;
#pragma unroll
        for (int jd = 0; jd < 4; jd++) zp[jd * 16] = f2bf(oacc[jd][r] * inv);
    }
}

// ---------------- launcher ----------------

extern "C" void kernel_launch(void* const* d_in, const int* in_sizes, int n_in,
                              void* d_out, int out_size, void* d_ws, size_t ws_size,
                              hipStream_t stream) {
    const float* x = (const float*)d_in[0];
    const int* mask = (const int*)d_in[1];
    const float* Wqkv = (const float*)d_in[2];
    const float* Wout = (const float*)d_in[3];
    const float* bout = (const float*)d_in[4];
    float* out = (float*)d_out;
    char* ws = (char*)d_ws;

    unsigned short* xz    = (unsigned short*)(ws);               // 8 MB (x bf16, later Z bf16)
    unsigned short* wqkvT = (unsigned short*)(ws + (8u << 20));  // 6 MB
    unsigned short* woutT = (unsigned short*)(ws + (14u << 20)); // 2 MB
    unsigned char*  m8    = (unsigned char*)(ws + (16u << 20));  // 8 MB
    unsigned short* Qb    = (unsigned short*)(ws + (24u << 20)); // 8 MB
    unsigned short* Kb    = (unsigned short*)(ws + (32u << 20)); // 8 MB
    unsigned short* VTb   = (unsigned short*)(ws + (40u << 20)); // 8 MB

    convx<<<4096, 256, 0, stream>>>(x, xz);
    transposew<<<dim3(3072 / 32, 1024 / 32), 256, 0, stream>>>(Wqkv, wqkvT, 1024, 3072);
    transposew<<<dim3(1024 / 32, 1024 / 32), 256, 0, stream>>>(Wout, woutT, 1024, 1024);
    packmask<<<8192, 256, 0, stream>>>(mask, (unsigned int*)m8);
    gemm_bf16<0><<<dim3(3072 / 128, 4096 / 128), 256, 0, stream>>>(
        xz, wqkvT, 4096, 3072, 1024, Qb, Kb, VTb, nullptr, nullptr);
    flash_attn<<<dim3(32, 32), 256, 0, stream>>>(Qb, Kb, VTb, m8, xz);
    gemm_bf16<1><<<dim3(1024 / 128, 4096 / 128), 256, 0, stream>>>(
        xz, woutT, 4096, 1024, 1024, nullptr, nullptr, nullptr, bout, out);
}